// Round 7
// baseline (609.012 us; speedup 1.0000x reference)
//
#include <hip/hip_runtime.h>

#define L_ 2
#define T_ 512
#define B_ 128
#define F_ 4
#define H_ 256
#define QSIGN_MASK 0x5390
#define LOG2E  1.4426950408889634f
#define LOG2E2 2.8853900817779268f

typedef __attribute__((ext_vector_type(8))) short short8;
typedef __attribute__((ext_vector_type(4))) float f32x4;

// Mailbox: layer-0 normalized output, bf16x4 packed per (t,b); norm-1 => nonzero.
__device__ unsigned long long g_inter_q[T_][B_];

__global__ void zero_inter() {
  ((unsigned long long*)g_inter_q)[blockIdx.x * 256 + threadIdx.x] = 0ull;
}

__device__ __forceinline__ unsigned f2bf(float f) {
  unsigned u = __float_as_uint(f);
  return (u + 0x7fff + ((u >> 16) & 1)) >> 16;
}
// R7: weights pre-scaled by log2e (sigmoid gates) / 2*log2e (c-gate), so the
// MFMA output y is already in the exp2 domain. sigma(pre) = rcp(1+2^-y);
// tanh(pre) = 2*sigma(2*pre)-1 = fma(2, rcp(1+2^-y), -1). No fabs/copysign,
// no per-call log2e mul; 2^-y's negate folds into the v_exp src modifier.
__device__ __forceinline__ float sig2(float y) {
  return __builtin_amdgcn_rcpf(1.f + __builtin_amdgcn_exp2f(-y));
}
__device__ __forceinline__ float tanh2(float y) {   // y = 2*log2e*z -> tanh(z)
  return fmaf(2.f, __builtin_amdgcn_rcpf(1.f + __builtin_amdgcn_exp2f(-y)), -1.f);
}
// RNE pack, identical rounding to f2bf, 2 instrs.
__device__ __forceinline__ unsigned long long pack4bf(float a, float b, float c, float d) {
  unsigned lo, hi;
  asm("v_cvt_pk_bf16_f32 %0, %1, %2" : "=v"(lo) : "v"(a), "v"(b));
  asm("v_cvt_pk_bf16_f32 %0, %1, %2" : "=v"(hi) : "v"(c), "v"(d));
  return ((unsigned long long)hi << 32) | lo;
}

union FragU { short8 v; uint4 u; unsigned w[4]; };

// Grid = 64 WGs x 320 threads (5 waves). blockIdx<32: layer-0 producer; else layer-1.
// R6 structure (session-best) + R7 local cuts:
//  - exp2-domain gates (weights pre-scaled), fma-form tanh.
//  - pre0[g] = bias + Wx.x_{s+1} computed at the TAIL of step s (x slot already
//    staged; MFMA pipe idle during gates) -> in-step chain is 8-deep and starts
//    directly on the h ds_reads, not on the sh_x read + Ax build.
// Compute waves 0-3: wave w owns cols u in [16w,16w+16). MFMA M rows = b*4+q
// (b=quad, q=reg in C/D), N = u16; LSTM update fully in-lane, one barrier/step.
// Helper wave 4: projection via MFMA; publishes mailbox every 2 steps; x/mailbox
// prefetch depth 2 into ring-4 sh_x.
__launch_bounds__(320, 1)
__global__ void qlstm_fused(const float* __restrict__ x_in,
                            const float* __restrict__ uhr, const float* __restrict__ uhi,
                            const float* __restrict__ uhj, const float* __restrict__ uhk,
                            const float* __restrict__ wxr, const float* __restrict__ wxi,
                            const float* __restrict__ wxj, const float* __restrict__ wxk,
                            const float* __restrict__ wxb_all,
                            const float* __restrict__ fcw_all, const float* __restrict__ fcb_all,
                            float* __restrict__ out_final)
{
  __shared__ __align__(16) unsigned short sh_h[2][4][272];  // double-buffered h (bf16)
  __shared__ unsigned long long sh_x[4][4];                 // ring-4 x, bf16x4 packed

  const int t     = threadIdx.x;
  const int role  = blockIdx.x >> 5;
  const int bg    = blockIdx.x & 31;
  const int bg0   = bg * 4;
  const int layer = role;
  const int wv    = t >> 6;
  const int lane  = t & 63;
  const int quad  = lane >> 4;
  const int sub   = lane & 15;

  const float* wb = wxb_all + layer * 4 * H_;
  const float* fw = fcw_all + layer * H_ * F_;
  const float* fb = fcb_all + layer * F_;

  for (int i = t; i < 2176; i += 320) ((unsigned short*)sh_h)[i] = 0;

  if (wv < 4) {
    // ================= COMPUTE WAVES =================
    const int u  = wv * 16 + sub;   // B n-col / D col
    const int ba = sub >> 2;        // A-side row -> batch
    const int qa = sub & 3;         // A-side row -> q

    // persistent B fragments [g][ks], scaled into the exp2 domain per gate
    FragU Bf[32];
    FragU Bx[4];
    f32x4 bvv[4];
    {
      const float* Cc[4] = {uhr, uhi, uhj, uhk};
      const float* Xc[4] = {wxr, wxi, wxj, wxk};
      #pragma unroll
      for (int g = 0; g < 4; ++g) {
        const float kg = (g == 3) ? LOG2E2 : LOG2E;
        #pragma unroll
        for (int ks = 0; ks < 8; ++ks) {
          const int d  = ks >> 1;
          const int pp = (ks & 1) * 32 + quad * 8;
          const float* src = Cc[d] + (size_t)((layer * 4 + g) * 64 + pp) * 64 + u;
          FragU f;
          #pragma unroll
          for (int j = 0; j < 8; ++j) f.v[j] = (short)f2bf(src[j * 64] * kg);
          Bf[g * 8 + ks] = f;
        }
        FragU fx; fx.w[0] = 0; fx.w[1] = 0; fx.w[2] = 0; fx.w[3] = 0;
        if (quad == 0) {
          unsigned e0 = f2bf(Xc[0][(layer * 4 + g) * 64 + u] * kg);
          unsigned e1 = f2bf(Xc[1][(layer * 4 + g) * 64 + u] * kg);
          unsigned e2 = f2bf(Xc[2][(layer * 4 + g) * 64 + u] * kg);
          unsigned e3 = f2bf(Xc[3][(layer * 4 + g) * 64 + u] * kg);
          fx.w[0] = e0 | (e1 << 16);
          fx.w[1] = e2 | (e3 << 16);
        }
        Bx[g] = fx;
        f32x4 bv;
        #pragma unroll
        for (int r = 0; r < 4; ++r) bv[r] = wb[g * 256 + r * 64 + u] * kg;
        bvv[g] = bv;
      }
    }
    // sign masks (a = qa^d) and A-read byte offsets
    unsigned smask[4], smx[4];
    int xsh[4], aoff[8];
    #pragma unroll
    for (int d = 0; d < 4; ++d) {
      const int a = qa ^ d;
      const bool neg = (QSIGN_MASK >> (a * 4 + qa)) & 1;
      smask[d] = neg ? 0x80008000u : 0u;
      smx[d]   = neg ? 0x8000u : 0u;
      xsh[d]   = 16 * a;
    }
    #pragma unroll
    for (int ks = 0; ks < 8; ++ks)
      aoff[ks] = ba * 544 + (((qa ^ (ks >> 1)) * 64 + (ks & 1) * 32 + quad * 8) << 1);
    float cs[4] = {0.f, 0.f, 0.f, 0.f};
    __syncthreads();

    // next-step preaccumulator: nx[g] = bias + Wx.x (x A-frag from sh_x slot)
    f32x4 nx0, nx1, nx2, nx3;
#define BUILD_PRE(slot) do { \
      unsigned long long xq = sh_x[slot][ba]; \
      FragU Ax; Ax.w[0] = 0; Ax.w[1] = 0; Ax.w[2] = 0; Ax.w[3] = 0; \
      if (quad == 0) { \
        unsigned e0 = ((unsigned)(xq >> xsh[0]) & 0xffffu) ^ smx[0]; \
        unsigned e1 = ((unsigned)(xq >> xsh[1]) & 0xffffu) ^ smx[1]; \
        unsigned e2 = ((unsigned)(xq >> xsh[2]) & 0xffffu) ^ smx[2]; \
        unsigned e3 = ((unsigned)(xq >> xsh[3]) & 0xffffu) ^ smx[3]; \
        Ax.w[0] = e0 | (e1 << 16); \
        Ax.w[1] = e2 | (e3 << 16); \
      } \
      nx0 = __builtin_amdgcn_mfma_f32_16x16x32_bf16(Ax.v, Bx[0].v, bvv[0], 0, 0, 0); \
      nx1 = __builtin_amdgcn_mfma_f32_16x16x32_bf16(Ax.v, Bx[1].v, bvv[1], 0, 0, 0); \
      nx2 = __builtin_amdgcn_mfma_f32_16x16x32_bf16(Ax.v, Bx[2].v, bvv[2], 0, 0, 0); \
      nx3 = __builtin_amdgcn_mfma_f32_16x16x32_bf16(Ax.v, Bx[3].v, bvv[3], 0, 0, 0); \
    } while (0)

    BUILD_PRE(0);   // x_0 staged in prologue; visible after the barrier above

    const char* hbB = (const char*)sh_h;
    for (int s = 0; s <= T_; ++s) {
      if (s < T_) {
        const char* hp = hbB + ((s + 1) & 1) * 2176;   // h[s-1]
        // 8-deep h-chain seeded by the preaccumulated bias + x-term
        f32x4 acc0 = nx0, acc1 = nx1, acc2 = nx2, acc3 = nx3;
        #pragma unroll
        for (int ks = 0; ks < 8; ++ks) {
          FragU A;
          A.u = *(const uint4*)(hp + aoff[ks]);
          const unsigned m = smask[ks >> 1];
          A.w[0] ^= m; A.w[1] ^= m; A.w[2] ^= m; A.w[3] ^= m;
          acc0 = __builtin_amdgcn_mfma_f32_16x16x32_bf16(A.v, Bf[0 * 8 + ks].v, acc0, 0, 0, 0);
          acc1 = __builtin_amdgcn_mfma_f32_16x16x32_bf16(A.v, Bf[1 * 8 + ks].v, acc1, 0, 0, 0);
          acc2 = __builtin_amdgcn_mfma_f32_16x16x32_bf16(A.v, Bf[2 * 8 + ks].v, acc2, 0, 0, 0);
          acc3 = __builtin_amdgcn_mfma_f32_16x16x32_bf16(A.v, Bf[3 * 8 + ks].v, acc3, 0, 0, 0);
        }
        // fully in-lane gates (exp2 domain): b=quad, c = r*64+u for r=0..3
        float hv0, hv1, hv2, hv3;
        {
          float fg, ig, og, cv;
          fg = sig2(acc0[0]); ig = sig2(acc1[0]); og = sig2(acc2[0]); cv = tanh2(acc3[0]);
          cs[0] = ig * cv + fg * cs[0]; hv0 = og * tanh2(cs[0] * LOG2E2);
          fg = sig2(acc0[1]); ig = sig2(acc1[1]); og = sig2(acc2[1]); cv = tanh2(acc3[1]);
          cs[1] = ig * cv + fg * cs[1]; hv1 = og * tanh2(cs[1] * LOG2E2);
          fg = sig2(acc0[2]); ig = sig2(acc1[2]); og = sig2(acc2[2]); cv = tanh2(acc3[2]);
          cs[2] = ig * cv + fg * cs[2]; hv2 = og * tanh2(cs[2] * LOG2E2);
          fg = sig2(acc0[3]); ig = sig2(acc1[3]); og = sig2(acc2[3]); cv = tanh2(acc3[3]);
          cs[3] = ig * cv + fg * cs[3]; hv3 = og * tanh2(cs[3] * LOG2E2);
        }
        unsigned w01, w23;
        asm("v_cvt_pk_bf16_f32 %0, %1, %2" : "=v"(w01) : "v"(hv0), "v"(hv1));
        asm("v_cvt_pk_bf16_f32 %0, %1, %2" : "=v"(w23) : "v"(hv2), "v"(hv3));
        char* hw = (char*)sh_h + (s & 1) * 2176 + quad * 544;
        const int ub = u << 1;
        *(unsigned short*)(hw + ub)       = (unsigned short)w01;
        *(unsigned short*)(hw + 128 + ub) = (unsigned short)(w01 >> 16);
        *(unsigned short*)(hw + 256 + ub) = (unsigned short)w23;
        *(unsigned short*)(hw + 384 + ub) = (unsigned short)(w23 >> 16);
        // tail: preaccumulate bias + x-term for step s+1 (MFMA pipe idle here;
        // slot (s+1)&3 was staged during step s-1 -> visible since last barrier)
        if (s + 1 < T_) BUILD_PRE((s + 1) & 3);
      }
      __syncthreads();
    }
#undef BUILD_PRE
  } else {
    // ================= HELPER WAVE =================
    // fw^T A-frags: A[m=f][k] = fw[k][f], rows 4-15 zero
    FragU Af[8];
    #pragma unroll
    for (int ks = 0; ks < 8; ++ks) {
      FragU f;
      #pragma unroll
      for (int j = 0; j < 8; ++j) {
        const int k = ks * 32 + quad * 8 + j;
        f.v[j] = (sub < 4) ? (short)f2bf(fw[k * 4 + sub]) : (short)0;
      }
      Af[ks] = f;
    }
    const float fb0 = fb[0], fb1 = fb[1], fb2 = fb[2], fb3 = fb[3];
    const int bl = sub & 3;   // B-side col (batch), clamped for lanes >= 4

    // prologue: x slots 0,1
    if (lane < 4) {
      #pragma unroll
      for (int s0 = 0; s0 < 2; ++s0) {
        if (role == 0) {
          float4 xv = *(const float4*)(x_in + (size_t)((bg0 + lane) * T_ + s0) * F_);
          sh_x[s0][lane] = pack4bf(xv.x, xv.y, xv.z, xv.w);
        } else {
          unsigned long long v;
          while ((v = __hip_atomic_load(&g_inter_q[s0][bg0 + lane], __ATOMIC_RELAXED,
                                        __HIP_MEMORY_SCOPE_AGENT)) == 0ull)
            __builtin_amdgcn_s_sleep(1);
          sh_x[s0][lane] = v;
        }
      }
    }
    unsigned long long heldq = 0ull;
    __syncthreads();

    for (int s = 0; s <= T_; ++s) {
      const bool doproj = (s >= 1) && (role == 0 || s == T_);
      if (doproj) {
        const char* hp = (const char*)sh_h + ((s + 1) & 1) * 2176;  // h[s-1]
        f32x4 pa = {fb0, fb1, fb2, fb3};
        #pragma unroll
        for (int ks = 0; ks < 8; ++ks) {
          FragU Bh;
          Bh.u = *(const uint4*)(hp + bl * 544 + ((ks * 32 + quad * 8) << 1));
          pa = __builtin_amdgcn_mfma_f32_16x16x32_bf16(Af[ks].v, Bh.v, pa, 0, 0, 0);
        }
        if (lane < 4) {   // quad==0, sub<4: all 4 components in-reg, batch = lane
          float p0 = pa[0], p1 = pa[1], p2 = pa[2], p3 = pa[3];
          float inv = __builtin_amdgcn_rsqf(
              fmaxf(p0*p0 + p1*p1 + p2*p2 + p3*p3, 1e-24f));
          p0 *= inv; p1 *= inv; p2 *= inv; p3 *= inv;
          if (role == 0) {
            unsigned long long qw = pack4bf(p0, p1, p2, p3);
            if (s & 1) {
              heldq = qw;              // idx s-1 held one step
            } else {                   // publish pair (s-2, s-1): one drain per 2 steps
              __hip_atomic_store(&g_inter_q[s - 2][bg0 + lane], heldq,
                                 __ATOMIC_RELAXED, __HIP_MEMORY_SCOPE_AGENT);
              __hip_atomic_store(&g_inter_q[s - 1][bg0 + lane], qw,
                                 __ATOMIC_RELAXED, __HIP_MEMORY_SCOPE_AGENT);
            }
          } else {                     // consumer, s == T: final output
            *(float4*)(out_final + (bg0 + lane) * F_) = make_float4(p0, p1, p2, p3);
          }
        }
      }
      if (lane < 4 && s + 2 < T_) {
        const int slot = (s + 2) & 3;
        if (role == 0) {
          float4 xv = *(const float4*)(x_in + (size_t)((bg0 + lane) * T_ + s + 2) * F_);
          sh_x[slot][lane] = pack4bf(xv.x, xv.y, xv.z, xv.w);
        } else {
          unsigned long long v;
          while ((v = __hip_atomic_load(&g_inter_q[s + 2][bg0 + lane], __ATOMIC_RELAXED,
                                        __HIP_MEMORY_SCOPE_AGENT)) == 0ull)
            __builtin_amdgcn_s_sleep(1);
          sh_x[slot][lane] = v;
        }
      }
      __syncthreads();
    }
  }
}

extern "C" void kernel_launch(void* const* d_in, const int* in_sizes, int n_in,
                              void* d_out, int out_size, void* d_ws, size_t ws_size,
                              hipStream_t stream) {
  const float* x   = (const float*)d_in[0];
  const float* wxr = (const float*)d_in[1];
  const float* wxi = (const float*)d_in[2];
  const float* wxj = (const float*)d_in[3];
  const float* wxk = (const float*)d_in[4];
  const float* wxb = (const float*)d_in[5];
  const float* uhr = (const float*)d_in[6];
  const float* uhi = (const float*)d_in[7];
  const float* uhj = (const float*)d_in[8];
  const float* uhk = (const float*)d_in[9];
  const float* fcw = (const float*)d_in[10];
  const float* fcb = (const float*)d_in[11];
  float* out = (float*)d_out;

  zero_inter<<<dim3(T_ * B_ / 256), dim3(256), 0, stream>>>();
  qlstm_fused<<<dim3(64), dim3(320), 0, stream>>>(
      x, uhr, uhi, uhj, uhk, wxr, wxi, wxj, wxk, wxb, fcw, fcb, out);
}

// Round 8
// 524.460 us; speedup vs baseline: 1.1612x; 1.1612x over previous
//
#include <hip/hip_runtime.h>

#define L_ 2
#define T_ 512
#define B_ 128
#define F_ 4
#define H_ 256
#define QSIGN_MASK 0x5390
#define LOG2E  1.4426950408889634f
#define LOG2E2 2.8853900817779268f

typedef __attribute__((ext_vector_type(8))) short short8;
typedef __attribute__((ext_vector_type(4))) float f32x4;

// Mailbox: layer-0 normalized output, bf16x4 packed per (t,b); norm-1 => nonzero.
__device__ unsigned long long g_inter_q[T_][B_];

__global__ void zero_inter() {
  ((unsigned long long*)g_inter_q)[blockIdx.x * 256 + threadIdx.x] = 0ull;
}

__device__ __forceinline__ unsigned f2bf(float f) {
  unsigned u = __float_as_uint(f);
  return (u + 0x7fff + ((u >> 16) & 1)) >> 16;
}
// Weights pre-scaled by log2e (sigmoid gates) / 2*log2e (c-gate): MFMA output y
// is already in the exp2 domain. sigma = rcp(1+2^-y); tanh = fma(2,rcp(1+2^-y),-1).
// R7 post-mortem: these are PROVEN (abs VALU 51.6->45.5us). The tail-BUILD_PRE
// placement is NOT (spill + exposed tail latency) - reverted to head here.
__device__ __forceinline__ float sig2(float y) {
  return __builtin_amdgcn_rcpf(1.f + __builtin_amdgcn_exp2f(-y));
}
__device__ __forceinline__ float tanh2(float y) {   // y = 2*log2e*z -> tanh(z)
  return fmaf(2.f, __builtin_amdgcn_rcpf(1.f + __builtin_amdgcn_exp2f(-y)), -1.f);
}
// RNE pack, identical rounding to f2bf, 2 instrs.
__device__ __forceinline__ unsigned long long pack4bf(float a, float b, float c, float d) {
  unsigned lo, hi;
  asm("v_cvt_pk_bf16_f32 %0, %1, %2" : "=v"(lo) : "v"(a), "v"(b));
  asm("v_cvt_pk_bf16_f32 %0, %1, %2" : "=v"(hi) : "v"(c), "v"(d));
  return ((unsigned long long)hi << 32) | lo;
}

union FragU { short8 v; uint4 u; unsigned w[4]; };

// Grid = 64 WGs x 320 threads (5 waves). blockIdx<32: layer-0 producer; else layer-1.
// R6 structure (session-best schedule) + exp2-domain gates (R7-proven).
// Compute waves 0-3: wave w owns cols u in [16w,16w+16). MFMA M rows = b*4+q
// (b=quad, q=reg in C/D), N = u16; x-MFMA at the HEAD of the step seeding the
// accumulators (overlaps with the h ds_reads; no state lives across the gate
// phase -> no spill). LSTM update fully in-lane, one barrier/step.
// Helper wave 4: projection via MFMA; publishes mailbox every 2 steps; x/mailbox
// prefetch depth 2 into ring-4 sh_x.
__launch_bounds__(320, 1)
__global__ void qlstm_fused(const float* __restrict__ x_in,
                            const float* __restrict__ uhr, const float* __restrict__ uhi,
                            const float* __restrict__ uhj, const float* __restrict__ uhk,
                            const float* __restrict__ wxr, const float* __restrict__ wxi,
                            const float* __restrict__ wxj, const float* __restrict__ wxk,
                            const float* __restrict__ wxb_all,
                            const float* __restrict__ fcw_all, const float* __restrict__ fcb_all,
                            float* __restrict__ out_final)
{
  __shared__ __align__(16) unsigned short sh_h[2][4][272];  // double-buffered h (bf16)
  __shared__ unsigned long long sh_x[4][4];                 // ring-4 x, bf16x4 packed

  const int t     = threadIdx.x;
  const int role  = blockIdx.x >> 5;
  const int bg    = blockIdx.x & 31;
  const int bg0   = bg * 4;
  const int layer = role;
  const int wv    = t >> 6;
  const int lane  = t & 63;
  const int quad  = lane >> 4;
  const int sub   = lane & 15;

  const float* wb = wxb_all + layer * 4 * H_;
  const float* fw = fcw_all + layer * H_ * F_;
  const float* fb = fcb_all + layer * F_;

  for (int i = t; i < 2176; i += 320) ((unsigned short*)sh_h)[i] = 0;

  if (wv < 4) {
    // ================= COMPUTE WAVES =================
    const int u  = wv * 16 + sub;   // B n-col / D col
    const int ba = sub >> 2;        // A-side row -> batch
    const int qa = sub & 3;         // A-side row -> q

    // persistent B fragments [g][ks], scaled into the exp2 domain per gate
    FragU Bf[32];
    FragU Bx[4];
    f32x4 bvv[4];
    {
      const float* Cc[4] = {uhr, uhi, uhj, uhk};
      const float* Xc[4] = {wxr, wxi, wxj, wxk};
      #pragma unroll
      for (int g = 0; g < 4; ++g) {
        const float kg = (g == 3) ? LOG2E2 : LOG2E;
        #pragma unroll
        for (int ks = 0; ks < 8; ++ks) {
          const int d  = ks >> 1;
          const int pp = (ks & 1) * 32 + quad * 8;
          const float* src = Cc[d] + (size_t)((layer * 4 + g) * 64 + pp) * 64 + u;
          FragU f;
          #pragma unroll
          for (int j = 0; j < 8; ++j) f.v[j] = (short)f2bf(src[j * 64] * kg);
          Bf[g * 8 + ks] = f;
        }
        FragU fx; fx.w[0] = 0; fx.w[1] = 0; fx.w[2] = 0; fx.w[3] = 0;
        if (quad == 0) {
          unsigned e0 = f2bf(Xc[0][(layer * 4 + g) * 64 + u] * kg);
          unsigned e1 = f2bf(Xc[1][(layer * 4 + g) * 64 + u] * kg);
          unsigned e2 = f2bf(Xc[2][(layer * 4 + g) * 64 + u] * kg);
          unsigned e3 = f2bf(Xc[3][(layer * 4 + g) * 64 + u] * kg);
          fx.w[0] = e0 | (e1 << 16);
          fx.w[1] = e2 | (e3 << 16);
        }
        Bx[g] = fx;
        f32x4 bv;
        #pragma unroll
        for (int r = 0; r < 4; ++r) bv[r] = wb[g * 256 + r * 64 + u] * kg;
        bvv[g] = bv;
      }
    }
    // sign masks (a = qa^d) and A-read byte offsets
    unsigned smask[4], smx[4];
    int xsh[4], aoff[8];
    #pragma unroll
    for (int d = 0; d < 4; ++d) {
      const int a = qa ^ d;
      const bool neg = (QSIGN_MASK >> (a * 4 + qa)) & 1;
      smask[d] = neg ? 0x80008000u : 0u;
      smx[d]   = neg ? 0x8000u : 0u;
      xsh[d]   = 16 * a;
    }
    #pragma unroll
    for (int ks = 0; ks < 8; ++ks)
      aoff[ks] = ba * 544 + (((qa ^ (ks >> 1)) * 64 + (ks & 1) * 32 + quad * 8) << 1);
    float cs[4] = {0.f, 0.f, 0.f, 0.f};
    __syncthreads();

    const char* hbB = (const char*)sh_h;
    for (int s = 0; s <= T_; ++s) {
      if (s < T_) {
        const char* hp = hbB + ((s + 1) & 1) * 2176;   // h[s-1]
        // x A-frag: k=d (0..3), value = sign(a,q)*x[b][a], a=q^d
        unsigned long long xq = sh_x[s & 3][ba];
        FragU Ax; Ax.w[0] = 0; Ax.w[1] = 0; Ax.w[2] = 0; Ax.w[3] = 0;
        if (quad == 0) {
          unsigned e0 = ((unsigned)(xq >> xsh[0]) & 0xffffu) ^ smx[0];
          unsigned e1 = ((unsigned)(xq >> xsh[1]) & 0xffffu) ^ smx[1];
          unsigned e2 = ((unsigned)(xq >> xsh[2]) & 0xffffu) ^ smx[2];
          unsigned e3 = ((unsigned)(xq >> xsh[3]) & 0xffffu) ^ smx[3];
          Ax.w[0] = e0 | (e1 << 16);
          Ax.w[1] = e2 | (e3 << 16);
        }
        // bias enters as the MFMA C-operand (no acc-init movs)
        f32x4 acc0 = __builtin_amdgcn_mfma_f32_16x16x32_bf16(Ax.v, Bx[0].v, bvv[0], 0, 0, 0);
        f32x4 acc1 = __builtin_amdgcn_mfma_f32_16x16x32_bf16(Ax.v, Bx[1].v, bvv[1], 0, 0, 0);
        f32x4 acc2 = __builtin_amdgcn_mfma_f32_16x16x32_bf16(Ax.v, Bx[2].v, bvv[2], 0, 0, 0);
        f32x4 acc3 = __builtin_amdgcn_mfma_f32_16x16x32_bf16(Ax.v, Bx[3].v, bvv[3], 0, 0, 0);
        #pragma unroll
        for (int ks = 0; ks < 8; ++ks) {
          FragU A;
          A.u = *(const uint4*)(hp + aoff[ks]);
          const unsigned m = smask[ks >> 1];
          A.w[0] ^= m; A.w[1] ^= m; A.w[2] ^= m; A.w[3] ^= m;
          acc0 = __builtin_amdgcn_mfma_f32_16x16x32_bf16(A.v, Bf[0 * 8 + ks].v, acc0, 0, 0, 0);
          acc1 = __builtin_amdgcn_mfma_f32_16x16x32_bf16(A.v, Bf[1 * 8 + ks].v, acc1, 0, 0, 0);
          acc2 = __builtin_amdgcn_mfma_f32_16x16x32_bf16(A.v, Bf[2 * 8 + ks].v, acc2, 0, 0, 0);
          acc3 = __builtin_amdgcn_mfma_f32_16x16x32_bf16(A.v, Bf[3 * 8 + ks].v, acc3, 0, 0, 0);
        }
        // fully in-lane gates (exp2 domain): b=quad, c = r*64+u for r=0..3
        float hv0, hv1, hv2, hv3;
        {
          float fg, ig, og, cv;
          fg = sig2(acc0[0]); ig = sig2(acc1[0]); og = sig2(acc2[0]); cv = tanh2(acc3[0]);
          cs[0] = ig * cv + fg * cs[0]; hv0 = og * tanh2(cs[0] * LOG2E2);
          fg = sig2(acc0[1]); ig = sig2(acc1[1]); og = sig2(acc2[1]); cv = tanh2(acc3[1]);
          cs[1] = ig * cv + fg * cs[1]; hv1 = og * tanh2(cs[1] * LOG2E2);
          fg = sig2(acc0[2]); ig = sig2(acc1[2]); og = sig2(acc2[2]); cv = tanh2(acc3[2]);
          cs[2] = ig * cv + fg * cs[2]; hv2 = og * tanh2(cs[2] * LOG2E2);
          fg = sig2(acc0[3]); ig = sig2(acc1[3]); og = sig2(acc2[3]); cv = tanh2(acc3[3]);
          cs[3] = ig * cv + fg * cs[3]; hv3 = og * tanh2(cs[3] * LOG2E2);
        }
        unsigned w01, w23;
        asm("v_cvt_pk_bf16_f32 %0, %1, %2" : "=v"(w01) : "v"(hv0), "v"(hv1));
        asm("v_cvt_pk_bf16_f32 %0, %1, %2" : "=v"(w23) : "v"(hv2), "v"(hv3));
        char* hw = (char*)sh_h + (s & 1) * 2176 + quad * 544;
        const int ub = u << 1;
        *(unsigned short*)(hw + ub)       = (unsigned short)w01;
        *(unsigned short*)(hw + 128 + ub) = (unsigned short)(w01 >> 16);
        *(unsigned short*)(hw + 256 + ub) = (unsigned short)w23;
        *(unsigned short*)(hw + 384 + ub) = (unsigned short)(w23 >> 16);
      }
      __syncthreads();
    }
  } else {
    // ================= HELPER WAVE =================
    // fw^T A-frags: A[m=f][k] = fw[k][f], rows 4-15 zero
    FragU Af[8];
    #pragma unroll
    for (int ks = 0; ks < 8; ++ks) {
      FragU f;
      #pragma unroll
      for (int j = 0; j < 8; ++j) {
        const int k = ks * 32 + quad * 8 + j;
        f.v[j] = (sub < 4) ? (short)f2bf(fw[k * 4 + sub]) : (short)0;
      }
      Af[ks] = f;
    }
    const float fb0 = fb[0], fb1 = fb[1], fb2 = fb[2], fb3 = fb[3];
    const int bl = sub & 3;   // B-side col (batch), clamped for lanes >= 4

    // prologue: x slots 0,1
    if (lane < 4) {
      #pragma unroll
      for (int s0 = 0; s0 < 2; ++s0) {
        if (role == 0) {
          float4 xv = *(const float4*)(x_in + (size_t)((bg0 + lane) * T_ + s0) * F_);
          sh_x[s0][lane] = pack4bf(xv.x, xv.y, xv.z, xv.w);
        } else {
          unsigned long long v;
          while ((v = __hip_atomic_load(&g_inter_q[s0][bg0 + lane], __ATOMIC_RELAXED,
                                        __HIP_MEMORY_SCOPE_AGENT)) == 0ull)
            __builtin_amdgcn_s_sleep(1);
          sh_x[s0][lane] = v;
        }
      }
    }
    unsigned long long heldq = 0ull;
    __syncthreads();

    for (int s = 0; s <= T_; ++s) {
      const bool doproj = (s >= 1) && (role == 0 || s == T_);
      if (doproj) {
        const char* hp = (const char*)sh_h + ((s + 1) & 1) * 2176;  // h[s-1]
        f32x4 pa = {fb0, fb1, fb2, fb3};
        #pragma unroll
        for (int ks = 0; ks < 8; ++ks) {
          FragU Bh;
          Bh.u = *(const uint4*)(hp + bl * 544 + ((ks * 32 + quad * 8) << 1));
          pa = __builtin_amdgcn_mfma_f32_16x16x32_bf16(Af[ks].v, Bh.v, pa, 0, 0, 0);
        }
        if (lane < 4) {   // quad==0, sub<4: all 4 components in-reg, batch = lane
          float p0 = pa[0], p1 = pa[1], p2 = pa[2], p3 = pa[3];
          float inv = __builtin_amdgcn_rsqf(
              fmaxf(p0*p0 + p1*p1 + p2*p2 + p3*p3, 1e-24f));
          p0 *= inv; p1 *= inv; p2 *= inv; p3 *= inv;
          if (role == 0) {
            unsigned long long qw = pack4bf(p0, p1, p2, p3);
            if (s & 1) {
              heldq = qw;              // idx s-1 held one step
            } else {                   // publish pair (s-2, s-1): one drain per 2 steps
              __hip_atomic_store(&g_inter_q[s - 2][bg0 + lane], heldq,
                                 __ATOMIC_RELAXED, __HIP_MEMORY_SCOPE_AGENT);
              __hip_atomic_store(&g_inter_q[s - 1][bg0 + lane], qw,
                                 __ATOMIC_RELAXED, __HIP_MEMORY_SCOPE_AGENT);
            }
          } else {                     // consumer, s == T: final output
            *(float4*)(out_final + (bg0 + lane) * F_) = make_float4(p0, p1, p2, p3);
          }
        }
      }
      if (lane < 4 && s + 2 < T_) {
        const int slot = (s + 2) & 3;
        if (role == 0) {
          float4 xv = *(const float4*)(x_in + (size_t)((bg0 + lane) * T_ + s + 2) * F_);
          sh_x[slot][lane] = pack4bf(xv.x, xv.y, xv.z, xv.w);
        } else {
          unsigned long long v;
          while ((v = __hip_atomic_load(&g_inter_q[s + 2][bg0 + lane], __ATOMIC_RELAXED,
                                        __HIP_MEMORY_SCOPE_AGENT)) == 0ull)
            __builtin_amdgcn_s_sleep(1);
          sh_x[slot][lane] = v;
        }
      }
      __syncthreads();
    }
  }
}

extern "C" void kernel_launch(void* const* d_in, const int* in_sizes, int n_in,
                              void* d_out, int out_size, void* d_ws, size_t ws_size,
                              hipStream_t stream) {
  const float* x   = (const float*)d_in[0];
  const float* wxr = (const float*)d_in[1];
  const float* wxi = (const float*)d_in[2];
  const float* wxj = (const float*)d_in[3];
  const float* wxk = (const float*)d_in[4];
  const float* wxb = (const float*)d_in[5];
  const float* uhr = (const float*)d_in[6];
  const float* uhi = (const float*)d_in[7];
  const float* uhj = (const float*)d_in[8];
  const float* uhk = (const float*)d_in[9];
  const float* fcw = (const float*)d_in[10];
  const float* fcb = (const float*)d_in[11];
  float* out = (float*)d_out;

  zero_inter<<<dim3(T_ * B_ / 256), dim3(256), 0, stream>>>();
  qlstm_fused<<<dim3(64), dim3(320), 0, stream>>>(
      x, uhr, uhi, uhj, uhk, wxr, wxi, wxj, wxk, wxb, fcw, fcb, out);
}